// Round 4
// baseline (185.302 us; speedup 1.0000x reference)
//
#include <hip/hip_runtime.h>
#include <math.h>

#define NRES   126
#define CHUNK  21            // 126 = 6*21, 21 % 3 == 0
#define NCHUNK 6
#define ROWS   64            // one wave per block
#define OUTF   63            // 3*CHUNK output floats per thread per chunk
#define ISSUES 21            // DMA issues per array per chunk: 64*21/64

#define LGKM0()   asm volatile("s_waitcnt lgkmcnt(0)" ::: "memory")
#define VMWAIT42() asm volatile("s_waitcnt vmcnt(42)" ::: "memory")
#define VM0()     asm volatile("s_waitcnt vmcnt(0)" ::: "memory")

// async global->LDS DMA, 4 bytes/lane; LDS dest = uniform base + lane*4,
// global src is per-lane.
__device__ __forceinline__ void dma4(const float* g, float* l) {
    __builtin_amdgcn_global_load_lds(
        (const __attribute__((address_space(1))) void*)(g),
        (__attribute__((address_space(3))) void*)(l),
        4, 0, 0);
}

// 1/max(sqrt(x),1e-12) == rsqrt(max(x,1e-24)); rsq ~1 ulp.
__device__ __forceinline__ float guarded_rsqrt(float x) {
    return __builtin_amdgcn_rsqf(fmaxf(x, 1e-24f));
}

__device__ __forceinline__ void nerf_step(
    float s, float co, float rc, float bs,
    float &ax, float &ay, float &az,
    float &bx, float &by, float &bz,
    float &cx, float &cy, float &cz,
    float &dx, float &dy, float &dz)
{
    float rnt = __builtin_amdgcn_rsqf(s * s + co * co + 1e-8f);
    s  *= rnt;
    co *= rnt;
    float r1 =  bs * co;
    float r2 = -(bs * s);

    float ux = bx - cx + 1e-8f;
    float uy = by - cy + 1e-8f;
    float uz = bz - cz + 1e-8f;
    float ru = guarded_rsqrt(ux * ux + uy * uy + uz * uz);
    ux *= ru; uy *= ru; uz *= ru;

    float vx = bx - ax;
    float vy = by - ay;
    float vz = bz - az;
    float nx = vy * uz - vz * uy + 1e-8f;
    float ny = vz * ux - vx * uz + 1e-8f;
    float nz = vx * uy - vy * ux + 1e-8f;
    float rn = guarded_rsqrt(nx * nx + ny * ny + nz * nz);
    nx *= rn; ny *= rn; nz *= rn;

    float mx = ny * uz - nz * uy;
    float my = nz * ux - nx * uz;
    float mz = nx * uy - ny * ux;

    dx = cx + rc * ux + r1 * mx + r2 * nx;
    dy = cy + rc * uy + r1 * my + r2 * ny;
    dz = cz + rc * uz + r1 * mz + r2 * nz;

    ax = bx; ay = by; az = bz;
    bx = cx; by = cy; bz = cz;
    cx = dx; cy = dy; cz = dz;
}

__global__ __launch_bounds__(ROWS, 1) void DihedralToCartesian_kernel(
    const float* __restrict__ angles,   // (B, 252): [0:126)=sin, [126:252)=cos
    const float* __restrict__ prev,     // (B, 3, 3)
    float* __restrict__ out,            // (B, 126, 3)
    int nrows)
{
    // ring slots: [slot][r*21 + j], stride 21 (odd) -> conflict-free reads
    __shared__ float s_sin[2][ROWS * CHUNK];   // 10.5 KB
    __shared__ float s_cos[2][ROWS * CHUNK];   // 10.5 KB
    __shared__ float s_out[ROWS * OUTF];       // 15.75 KB -> 37.6 KB total, 4 blocks/CU

    const int t  = threadIdx.x;
    const int b0 = blockIdx.x * ROWS;

    // Stage chunk c into slot sl: gather each row's [c*21, c*21+21) sin/cos
    // into LDS layout [r][j].  flat = i*64 + t;  r = flat/21, j = flat%21.
    auto stage = [&](int c, int sl) {
        int r0 = t / 21;                       // 0..3
        int j  = t - r0 * 21;
        const float* gs = angles + (size_t)(b0 + r0) * 252 + c * 21 + j;
        #pragma unroll
        for (int i = 0; i < ISSUES; ++i) {
            dma4(gs,       &s_sin[sl][i * 64]);
            dma4(gs + 126, &s_cos[sl][i * 64]);
            int carry = (j >= 20) ? 1 : 0;     // flat += 64 = 3*21 + 1
            j += 1 - carry * 21;
            gs += 757 + carry * 231;           // 3*252+1 (+252-21 on carry)
        }
    };

    // prologue: first two chunks in flight, prev loads, one full drain
    stage(0, 0);
    stage(1, 1);

    const float* pr = prev + (size_t)(b0 + t) * 9;
    float ax = pr[0], ay = pr[1], az = pr[2];
    float bx = pr[3], by = pr[4], bz = pr[5];
    float cx = pr[6], cy = pr[7], cz = pr[8];

    VM0();   // chunks 0,1 resident; prev loaded; no stores outstanding yet

    const float rc0 = 1.329f * cosf(2.028f), bs0 = 1.329f * sinf(2.028f);
    const float rc1 = 1.458f * cosf(2.124f), bs1 = 1.458f * sinf(2.124f);
    const float rc2 = 1.523f * cosf(1.941f), bs2 = 1.523f * sinf(1.941f);

    #pragma unroll 1
    for (int k = 0; k < NCHUNK; ++k) {
        const int sl = k & 1;

        // chunk k guaranteed resident: it is older than last iter's 63 stores
        // and the in-flight prefetch (newest 42); wait outstanding <= 42.
        VMWAIT42();

        const float* ssin = &s_sin[sl][t * CHUNK];
        const float* scos = &s_cos[sl][t * CHUNK];

        float o[OUTF];
        float dx, dy, dz;
        #pragma unroll
        for (int j = 0; j < CHUNK; ++j) {
            float s  = ssin[j];
            float co = scos[j];
            const int ph = j % 3;              // compile-time (unrolled)
            const float rc = (ph == 0) ? rc0 : (ph == 1) ? rc1 : rc2;
            const float bs = (ph == 0) ? bs0 : (ph == 1) ? bs1 : bs2;
            nerf_step(s, co, rc, bs, ax, ay, az, bx, by, bz, cx, cy, cz, dx, dy, dz);
            o[3 * j + 0] = dx;
            o[3 * j + 1] = dy;
            o[3 * j + 2] = dz;
        }

        // stage outputs: stride 63 (odd) -> conflict-free
        #pragma unroll
        for (int q = 0; q < OUTF; ++q)
            s_out[t * OUTF + q] = o[q];

        LGKM0();   // s_out visible wave-wide (single-wave block: no barrier)

        // coalesced store: flat idx = p*64 + t; r = idx/63, jj = idx%63
        {
            int r0  = (t >= 63) ? 1 : 0;
            int jj  = t - r0 * 63;
            float* op = out + (size_t)b0 * 378 + (size_t)k * 63 + (size_t)r0 * 378 + jj;
            #pragma unroll
            for (int p = 0; p < OUTF; ++p) {
                op[0] = s_out[p * 64 + t];
                int carry = (jj >= 62) ? 1 : 0;    // flat += 64 = 63 + 1
                jj += 1 - carry * 63;
                op += 379 + carry * 315;           // 378+1 (+378-63 on carry)
            }
        }

        LGKM0();   // all LDS reads (inputs + s_out) retired before overwrite

        if (k + 2 < NCHUNK)
            stage(k + 2, sl);   // refill the slot we just finished reading
    }
}

extern "C" void kernel_launch(void* const* d_in, const int* in_sizes, int n_in,
                              void* d_out, int out_size, void* d_ws, size_t ws_size,
                              hipStream_t stream)
{
    const float* angles = (const float*)d_in[0];
    const float* prev   = (const float*)d_in[1];
    float*       out    = (float*)d_out;

    int nrows = in_sizes[1] / 9;        // B = 65536, divisible by ROWS
    int grid  = nrows / ROWS;           // 1024 single-wave blocks

    DihedralToCartesian_kernel<<<grid, ROWS, 0, stream>>>(angles, prev, out, nrows);
}

// Round 6
// 174.396 us; speedup vs baseline: 1.0625x; 1.0625x over previous
//
#include <hip/hip_runtime.h>
#include <math.h>

#define NRES 126
#define SEGS 14           // segments per row
#define SLEN 9            // steps per segment; SEGS*SLEN = 126, SLEN % 3 == 0
#define RPB  32           // rows per block
#define TPB  (RPB * SEGS) // 448 threads = 7 waves

// 1/max(sqrt(x),1e-12) == rsqrt(max(x,1e-24)); rsq ~1 ulp.
__device__ __forceinline__ float grsq(float x) {
    return __builtin_amdgcn_rsqf(fmaxf(x, 1e-24f));
}

__global__ __launch_bounds__(TPB, 4) void DihedralToCartesian_kernel(
    const float* __restrict__ angles,   // (B, 252): [0:126)=sin, [126:252)=cos
    const float* __restrict__ prev,     // (B, 3, 3)
    float* __restrict__ out,            // (B, 126, 3)
    int nrows)
{
    // Affine = R[9] row-major + t[3].  E[t]: segment transform / scan slot.
    __shared__ float E[TPB][13];        // 23.3 KB (pad 13: odd stride)
    __shared__ float F0[RPB][13];       // 1.7 KB

    if (blockIdx.x * RPB >= nrows) return;   // uniform (never taken: exact grid)

    const int t   = threadIdx.x;
    const int s   = t % SEGS;                // segment id
    const int rl  = t / SEGS;                // local row
    const int row = blockIdx.x * RPB + rl;

    // ---- load this segment's 9 sin + 9 cos (lanes are memory-adjacent) ----
    const float* ga = angles + (size_t)row * 252 + s * SLEN;
    float sn[SLEN], cs[SLEN];
    #pragma unroll
    for (int j = 0; j < SLEN; ++j) { sn[j] = ga[j]; cs[j] = ga[126 + j]; }

    // ---- F0 from prev_three (one lane per row), exactly per reference ----
    if (s == 0) {
        const float* pr = prev + (size_t)row * 9;
        float a0=pr[0],a1=pr[1],a2=pr[2];
        float b0=pr[3],b1=pr[4],b2=pr[5];
        float c0=pr[6],c1=pr[7],c2=pr[8];
        float ux=b0-c0+1e-8f, uy=b1-c1+1e-8f, uz=b2-c2+1e-8f;
        float ru=grsq(ux*ux+uy*uy+uz*uz); ux*=ru; uy*=ru; uz*=ru;
        float vx=b0-a0, vy=b1-a1, vz=b2-a2;
        float nx=vy*uz-vz*uy+1e-8f, ny=vz*ux-vx*uz+1e-8f, nz=vx*uy-vy*ux+1e-8f;
        float rn=grsq(nx*nx+ny*ny+nz*nz); nx*=rn; ny*=rn; nz*=rn;
        float mx=ny*uz-nz*uy, my=nz*ux-nx*uz, mz=nx*uy-ny*ux;
        float* f = F0[rl];                 // R cols = [bc | m1 | n], t = c
        f[0]=ux; f[1]=mx; f[2]=nx;
        f[3]=uy; f[4]=my; f[5]=ny;
        f[6]=uz; f[7]=mz; f[8]=nz;
        f[9]=c0; f[10]=c1; f[11]=c2;
    }

    // 3-periodic constants (i%3 == j%3 since SLEN%3==0); folded at compile time.
    const float ca0=cosf(2.028f), sa0=sinf(2.028f), bc0=1.329f*ca0, bs0=1.329f*sa0;
    const float ca1=cosf(2.124f), sa1=sinf(2.124f), bc1=1.458f*ca1, bs1=1.458f*sa1;
    const float ca2=cosf(1.941f), sa2=sinf(1.941f), bc2=1.523f*ca2, bs2=1.523f*sa2;

    // ---- phase 1: compose the segment's 9 local affines; record local points ----
    float r0,r1,r2,r3,r4,r5,r6,r7,r8, tx,ty,tz;
    float p[3 * SLEN];

    #pragma unroll
    for (int j = 0; j < SLEN; ++j) {
        const int ph = j % 3;              // compile-time (unrolled)
        const float ca  = (ph==0)?ca0:(ph==1)?ca1:ca2;
        const float sa  = (ph==0)?sa0:(ph==1)?sa1:sa2;
        const float bca = (ph==0)?bc0:(ph==1)?bc1:bc2;
        const float bsa = (ph==0)?bs0:(ph==1)?bs1:bs2;

        float rr = __builtin_amdgcn_rsqf(sn[j]*sn[j] + cs[j]*cs[j] + 1e-8f);
        float st = sn[j]*rr, ct = cs[j]*rr;
        // local affine A: M = [[-ca, sa, 0],[-sa*ct,-ca*ct, st],[ sa*st, ca*st, ct]]
        //                 t = (bca, bsa*ct, -bsa*st)
        float m10=-sa*ct, m11=-ca*ct, m20=sa*st, m21=ca*st;
        float tl1=bsa*ct, tl2=-bsa*st;

        if (j == 0) {
            r0=-ca;  r1=sa;   r2=0.f;
            r3=m10;  r4=m11;  r5=st;
            r6=m20;  r7=m21;  r8=ct;
            tx=bca;  ty=tl1;  tz=tl2;
        } else {
            // F <- F * A
            float n0 = r0*(-ca) + r1*m10 + r2*m20;
            float n1 = r0*sa    + r1*m11 + r2*m21;
            float n2 =            r1*st  + r2*ct;
            float n3 = r3*(-ca) + r4*m10 + r5*m20;
            float n4 = r3*sa    + r4*m11 + r5*m21;
            float n5 =            r4*st  + r5*ct;
            float n6 = r6*(-ca) + r7*m10 + r8*m20;
            float n7 = r6*sa    + r7*m11 + r8*m21;
            float n8 =            r7*st  + r8*ct;
            float q0 = tx + r0*bca + r1*tl1 + r2*tl2;
            float q1 = ty + r3*bca + r4*tl1 + r5*tl2;
            float q2 = tz + r6*bca + r7*tl1 + r8*tl2;
            r0=n0; r1=n1; r2=n2; r3=n3; r4=n4; r5=n5; r6=n6; r7=n7; r8=n8;
            tx=q0; ty=q1; tz=q2;
        }
        p[3*j+0]=tx; p[3*j+1]=ty; p[3*j+2]=tz;
    }

    // ---- phase 2: Hillis-Steele inclusive scan of segment transforms ----
    {
        float* e = E[t];
        e[0]=r0; e[1]=r1; e[2]=r2; e[3]=r3; e[4]=r4; e[5]=r5;
        e[6]=r6; e[7]=r7; e[8]=r8; e[9]=tx; e[10]=ty; e[11]=tz;
    }
    __syncthreads();

    #pragma unroll
    for (int l = 0; l < 4; ++l) {
        const int d = 1 << l;              // 1,2,4,8 (covers SEGS=14)
        const bool act = (s >= d);
        float A[12];
        if (act) {
            const float* a = E[t - d];
            #pragma unroll
            for (int w = 0; w < 12; ++w) A[w] = a[w];
            // X <- A * X   (A is the earlier block)
            float n0 = A[0]*r0 + A[1]*r3 + A[2]*r6;
            float n1 = A[0]*r1 + A[1]*r4 + A[2]*r7;
            float n2 = A[0]*r2 + A[1]*r5 + A[2]*r8;
            float n3 = A[3]*r0 + A[4]*r3 + A[5]*r6;
            float n4 = A[3]*r1 + A[4]*r4 + A[5]*r7;
            float n5 = A[3]*r2 + A[4]*r5 + A[5]*r8;
            float n6 = A[6]*r0 + A[7]*r3 + A[8]*r6;
            float n7 = A[6]*r1 + A[7]*r4 + A[8]*r7;
            float n8 = A[6]*r2 + A[7]*r5 + A[8]*r8;
            float q0 = A[9]  + A[0]*tx + A[1]*ty + A[2]*tz;
            float q1 = A[10] + A[3]*tx + A[4]*ty + A[5]*tz;
            float q2 = A[11] + A[6]*tx + A[7]*ty + A[8]*tz;
            r0=n0; r1=n1; r2=n2; r3=n3; r4=n4; r5=n5; r6=n6; r7=n7; r8=n8;
            tx=q0; ty=q1; tz=q2;
        }
        __syncthreads();
        if (act) {
            float* e = E[t];
            e[0]=r0; e[1]=r1; e[2]=r2; e[3]=r3; e[4]=r4; e[5]=r5;
            e[6]=r6; e[7]=r7; e[8]=r8; e[9]=tx; e[10]=ty; e[11]=tz;
        }
        __syncthreads();
    }

    // ---- phase 3: P = F0 (s==0) or F0 * incl[s-1]; apply to local points ----
    float P0,P1,P2,P3,P4,P5,P6,P7,P8, Pt0,Pt1,Pt2;
    {
        const float* f = F0[rl];
        if (s == 0) {
            P0=f[0]; P1=f[1]; P2=f[2];
            P3=f[3]; P4=f[4]; P5=f[5];
            P6=f[6]; P7=f[7]; P8=f[8];
            Pt0=f[9]; Pt1=f[10]; Pt2=f[11];
        } else {
            const float* b = E[t - 1];
            P0 = f[0]*b[0] + f[1]*b[3] + f[2]*b[6];
            P1 = f[0]*b[1] + f[1]*b[4] + f[2]*b[7];
            P2 = f[0]*b[2] + f[1]*b[5] + f[2]*b[8];
            P3 = f[3]*b[0] + f[4]*b[3] + f[5]*b[6];
            P4 = f[3]*b[1] + f[4]*b[4] + f[5]*b[7];
            P5 = f[3]*b[2] + f[4]*b[5] + f[5]*b[8];
            P6 = f[6]*b[0] + f[7]*b[3] + f[8]*b[6];
            P7 = f[6]*b[1] + f[7]*b[4] + f[8]*b[7];
            P8 = f[6]*b[2] + f[7]*b[5] + f[8]*b[8];
            Pt0 = f[9]  + f[0]*b[9] + f[1]*b[10] + f[2]*b[11];
            Pt1 = f[10] + f[3]*b[9] + f[4]*b[10] + f[5]*b[11];
            Pt2 = f[11] + f[6]*b[9] + f[7]*b[10] + f[8]*b[11];
        }
    }

    float* go = out + (size_t)row * 378 + s * 27;   // points s*9 .. s*9+8
    #pragma unroll
    for (int j = 0; j < SLEN; ++j) {
        float px=p[3*j], py=p[3*j+1], pz=p[3*j+2];
        go[3*j+0] = Pt0 + P0*px + P1*py + P2*pz;
        go[3*j+1] = Pt1 + P3*px + P4*py + P5*pz;
        go[3*j+2] = Pt2 + P6*px + P7*py + P8*pz;
    }
}

extern "C" void kernel_launch(void* const* d_in, const int* in_sizes, int n_in,
                              void* d_out, int out_size, void* d_ws, size_t ws_size,
                              hipStream_t stream)
{
    const float* angles = (const float*)d_in[0];
    const float* prev   = (const float*)d_in[1];
    float*       out    = (float*)d_out;

    int nrows = in_sizes[1] / 9;            // B = 65536
    int grid  = (nrows + RPB - 1) / RPB;    // 2048 blocks x 7 waves

    DihedralToCartesian_kernel<<<grid, TPB, 0, stream>>>(angles, prev, out, nrows);
}